// Round 12
// baseline (267.436 us; speedup 1.0000x reference)
//
#include <hip/hip_runtime.h>
#include <hip/hip_bf16.h>
#include <hip/hip_fp16.h>

#define N_NODES 50000
#define E_EDGES 1600000
#define IN_CH 128
#define HID 32
#define HEADS 4
#define HC (HEADS * HID)         // 128
#define OUT_CH 16
#define B_GRAPHS 512
#define NEG_SLOPE 0.2f
#define CAP 96                   // per-node capacity; deg = 1+Pois(32), P(>96)~1e-18
#define NB 512                   // coarse buckets (R15: 2 blocks/CU in k_aggB)
#define BNODES 98                // nodes per bucket (512*98 = 50176 >= 50000)
#define PCAP 3552                // per-bucket edge capacity (mean 3125 + 7.6 sd)
#define ACHUNK 4096              // edges per pass-A block
#define APART 391                // ceil(E_EDGES / ACHUNK)
#define ROWS_PB 64
#define GEMM_BLOCKS 782          // ceil(50000 / 64)
#define TOT_BLOCKS 1173          // APART + GEMM_BLOCKS, interleaved 1:2

// R20 LESSON: __threadfence() on per-block paths = per-wave L2 writeback,
// 5.5x. BUT __syncthreads() already drains vmcnt (atomics committed) — the
// fold mechanism is sound with barrier-drain + ticket, no fence. (R26)
// R21 LESSON: source-level load prefetch gets compiler-canonicalized away.
// R22 LESSON: passA+gemm interleaved-in-one-kernel beats sequential ~7 µs.
// R23 LESSON: 8->16 outstanding gathers = no change — k_aggB issue-bound.
// R24 LESSON: readfirstlane on LDS values = per-value lgkmcnt waits. No.

typedef short bfrag __attribute__((ext_vector_type(8)));   // 8 bf16 = 4 VGPR
typedef float facc  __attribute__((ext_vector_type(4)));   // MFMA 16x16 C/D

__device__ __forceinline__ unsigned short f2bf(float f) {
    unsigned int u = __float_as_uint(f);
    unsigned int r = (u + 0x7FFFu + ((u >> 16) & 1u)) >> 16;   // RNE
    return (unsigned short)r;
}

__device__ __forceinline__ float lrelu_exp(float v) {
    v = v > 0.f ? v : NEG_SLOPE * v;
    return __expf(v);
}

// split two fp32 into packed bf16 hi-pair and RNE lo-pair (R18-exact math)
__device__ __forceinline__ void split2(float a, float b,
                                       unsigned int& hi, unsigned int& lo) {
    unsigned int ua = __float_as_uint(a), ub = __float_as_uint(b);
    hi = (ua >> 16) | (ub & 0xFFFF0000u);
    float la = a - __uint_as_float(ua & 0xFFFF0000u);
    float lb = b - __uint_as_float(ub & 0xFFFF0000u);
    lo = (unsigned int)f2bf(la) | ((unsigned int)f2bf(lb) << 16);
}

// ---- K0: prep — W1 fp32 -> FRAGMENT-LINEAR bf16 hi/lo; zero gcur+ticket --
__global__ __launch_bounds__(256) void k_prep(const float* __restrict__ W1,
                                              unsigned short* __restrict__ whiF,
                                              unsigned short* __restrict__ wloF,
                                              int* __restrict__ gcur) {
    int tid = blockIdx.x * 256 + threadIdx.x;      // grid 64 -> 16384
    if (tid <= NB) gcur[tid] = 0;                  // gcur[0..511] + ticket[512]
    int e = tid & 7, l = (tid >> 3) & 63, q = tid >> 9;   // q = nt*4+kc
    int nt = q >> 2, kc = q & 3;
    int n = nt * 16 + (l & 15);
    int k = kc * 32 + (l >> 4) * 8 + e;
    float v = W1[k * 128 + n];
    unsigned int u = __float_as_uint(v);
    float lo_f = v - __uint_as_float(u & 0xFFFF0000u);  // exact residual
    whiF[tid] = (unsigned short)(u >> 16);              // truncated hi
    wloF[tid] = f2bf(lo_f);
}

// ---- K1: fused pass-A + split-bf16 MFMA GEMM, INTERLEAVED 1:2 ------------
// R25 structure: W-hi in LDS, W-lo streamed from L2, x straight to A-frags.
// Fragment layouts (gfx950 16x16x32): A: m=l&15, k=(l>>4)*8+e;
// B: n=l&15, k=(l>>4)*8+e; D: col=l&15, row=(l>>4)*4+r [R18-verified].
__global__ __launch_bounds__(256) void k_fused(const float* __restrict__ x,
                                               const unsigned short* __restrict__ whiF,
                                               const unsigned short* __restrict__ wloF,
                                               const float* __restrict__ att_src,
                                               const float* __restrict__ att_dst,
                                               const int* __restrict__ ei,
                                               unsigned short* __restrict__ hb,
                                               float* __restrict__ a_s,
                                               float* __restrict__ a_d,
                                               int* __restrict__ gcur,
                                               unsigned int* __restrict__ ebuf,
                                               float* __restrict__ g) {
    __shared__ float smem[8256];           // 33 KB: swh (32 KB) / sH[64][129] / pass-A 16 KB
    const int t = threadIdx.x;
    const int bI = blockIdx.x;

    if (bI % 3 == 0) {
        // ---- pass A with per-wave sub-histograms (16 KB of smem) ----
        const int ablk = bI / 3;           // 0..390
        int* scnt = (int*)smem;            // [4][NB] = 8 KB
        int* sbase = scnt + 4 * NB;        // [4][NB] = 8 KB
        const int wv = t >> 6;
        const int e0 = ablk * ACHUNK;
        int e1 = e0 + ACHUNK; if (e1 > E_EDGES) e1 = E_EDGES;
        for (int i = t; i < 4 * NB; i += 256) scnt[i] = 0;
        __syncthreads();
        const int* __restrict__ dstp = ei + E_EDGES;
        for (int e = e0 + t; e < e1; e += 256) {
            int d = dstp[e];
            atomicAdd(&scnt[wv * NB + d / BNODES], 1);
        }
        __syncthreads();
        for (int i = t; i < NB; i += 256) {
            int c0 = scnt[0 * NB + i], c1 = scnt[1 * NB + i];
            int c2 = scnt[2 * NB + i], c3 = scnt[3 * NB + i];
            int base = atomicAdd(&gcur[i], c0 + c1 + c2 + c3);
            sbase[0 * NB + i] = base;
            sbase[1 * NB + i] = base + c0;
            sbase[2 * NB + i] = base + c0 + c1;
            sbase[3 * NB + i] = base + c0 + c1 + c2;
            scnt[0 * NB + i] = 0; scnt[1 * NB + i] = 0;
            scnt[2 * NB + i] = 0; scnt[3 * NB + i] = 0;
        }
        __syncthreads();
        for (int e = e0 + t; e < e1; e += 256) {
            int d = dstp[e];
            int s = ei[e];
            int b = d / BNODES;
            int dl = d - b * BNODES;
            int pos = sbase[wv * NB + b] + atomicAdd(&scnt[wv * NB + b], 1);
            if (pos < PCAP)
                ebuf[(size_t)b * PCAP + pos] = ((unsigned int)dl << 16) | (unsigned int)s;
        }
        return;                            // uniform exit
    }

    // ---- GEMM part ----
    const int bid = bI - bI / 3 - 1;       // 0..781
    const int n0 = bid * ROWS_PB;

    int gt = bid * 256 + t;
    if (gt < B_GRAPHS * HC) g[gt] = 0.f;   // fused g-zero

    // stage whiF (32 KB) into LDS, coalesced
    unsigned short* swh = (unsigned short*)smem;       // [16384]
    {
        const uint4* wsrc = (const uint4*)whiF;
        uint4* wdst = (uint4*)swh;
#pragma unroll
        for (int it = 0; it < 8; it++)
            wdst[t + it * 256] = wsrc[t + it * 256];   // 2048 x 16B
    }

    const int wv = t >> 6, l = t & 63;
    const int lm = l & 15, lk = l >> 4;
    const int band = wv * 16;              // wave's 16-row band

    // A-frags straight from global (row private to this lane's wave)
    bfrag ahi[4], alo[4];
    {
        int row = n0 + band + lm;
        bool valid = row < N_NODES;
        const float* xr = x + (size_t)(valid ? row : 0) * IN_CH;
#pragma unroll
        for (int kc = 0; kc < 4; kc++) {
            float4 v0 = *(const float4*)(xr + kc * 32 + lk * 8);
            float4 v1 = *(const float4*)(xr + kc * 32 + lk * 8 + 4);
            if (!valid) { v0 = make_float4(0.f,0.f,0.f,0.f); v1 = v0; }
            union { bfrag f; unsigned int u[4]; } H, L;
            split2(v0.x, v0.y, H.u[0], L.u[0]);
            split2(v0.z, v0.w, H.u[1], L.u[1]);
            split2(v1.x, v1.y, H.u[2], L.u[2]);
            split2(v1.z, v1.w, H.u[3], L.u[3]);
            ahi[kc] = H.f; alo[kc] = L.f;
        }
    }

    facc acc[8];
#pragma unroll
    for (int nt = 0; nt < 8; nt++) acc[nt] = (facc){0.f, 0.f, 0.f, 0.f};

    __syncthreads();                       // swh staged

    {
        const int lb = l * 8;              // lane offset within each 1KB frag slab
#pragma unroll
        for (int q = 0; q < 32; q++) {     // q = nt*4+kc
            bfrag bhv = *(const bfrag*)(swh + q * 512 + lb);    // LDS
            bfrag blv = *(const bfrag*)(wloF + q * 512 + lb);   // L2
            const int nt = q >> 2, kc = q & 3;
            acc[nt] = __builtin_amdgcn_mfma_f32_16x16x32_bf16(ahi[kc], bhv, acc[nt], 0, 0, 0);
            acc[nt] = __builtin_amdgcn_mfma_f32_16x16x32_bf16(alo[kc], bhv, acc[nt], 0, 0, 0);
            acc[nt] = __builtin_amdgcn_mfma_f32_16x16x32_bf16(ahi[kc], blv, acc[nt], 0, 0, 0);
        }
    }

    // restash fp32 accs into sH[64][129] (D: row=band+lk*4+r, col=nt*16+lm)
    __syncthreads();                       // all swh reads done (sH aliases swh)
    float* sH = smem;
#pragma unroll
    for (int nt = 0; nt < 8; nt++) {
#pragma unroll
        for (int r = 0; r < 4; r++)
            sH[(band + lk * 4 + r) * 129 + nt * 16 + lm] = acc[nt][r];
    }
    __syncthreads();

    // hb store: coalesced ushort4 rows from sH
    for (int i = t; i < 64 * 32; i += 256) {
        int row = i >> 5, c4 = i & 31;
        const float* p = &sH[row * 129 + c4 * 4];
        int n = n0 + row;
        if (n < N_NODES) {
            ushort4 o;
            o.x = f2bf(p[0]); o.y = f2bf(p[1]);
            o.z = f2bf(p[2]); o.w = f2bf(p[3]);
            *(ushort4*)&hb[(size_t)n * HC + c4 * 4] = o;
        }
    }

    // score phase (proven): t<128, column-strided sH reads (conflict-free)
    if (t < 128) {
        int r = t & 63;
        int n = n0 + r;
        const float* __restrict__ av = (t < 64) ? att_src : att_dst;
        float s0 = 0.f, s1 = 0.f, s2 = 0.f, s3 = 0.f;
#pragma unroll 4
        for (int j = 0; j < 32; j++) {
            const float* row = &sH[r * 129 + j];
            s0 += row[0]  * av[j];
            s1 += row[32] * av[32 + j];
            s2 += row[64] * av[64 + j];
            s3 += row[96] * av[96 + j];
        }
        if (n < N_NODES) {
            float* dst = (t < 64) ? a_s : a_d;
            *(float4*)(dst + (size_t)n * 4) = make_float4(s0, s1, s2, s3);
        }
    }
}

// ---- K2: fused pass-B + aggregate + pool + (last block) MLP -------------
// R26: k_mlp folded via ticket. NO __threadfence — __syncthreads drains
// each wave's vmcnt (atomics committed at the coherent point) before t0
// increments the ticket. MLP mechanism correctness-proven in R20's run;
// g read AGENT-scope. Gather loop is R23-exact.
#define NPW 7                     // ceil(BNODES / 16); waves 14,15 idle
__global__ __launch_bounds__(1024) void k_aggB(const unsigned int* __restrict__ ebuf,
                                               const int* __restrict__ gcur,
                                               const float* __restrict__ a_s,
                                               const float* __restrict__ a_d,
                                               const unsigned short* __restrict__ hb,
                                               const float* __restrict__ b1,
                                               const int* __restrict__ batch,
                                               float* __restrict__ g,
                                               int* __restrict__ ticket,
                                               const float* __restrict__ lin1_w,
                                               const float* __restrict__ lin1_b,
                                               const float* __restrict__ lin2_w,
                                               const float* __restrict__ lin2_b,
                                               float* __restrict__ out) {
    __shared__ unsigned short sbuf[BNODES * CAP];   // 18816 B
    __shared__ int scnt[BNODES];                    //   392 B
    __shared__ float sWt[16][4][97];                // 24832 B  (~44 KB total)
    __shared__ int slast;
    const int t = threadIdx.x;
    const int b = blockIdx.x;
    const int dbase = b * BNODES;

    // phase 1: self-loop seed + LDS scatter of this bucket's edges
    for (int i = t; i < BNODES; i += 1024) {
        int d = dbase + i;
        scnt[i] = (d < N_NODES) ? 1 : 0;
        sbuf[i * CAP] = (unsigned short)d;
    }
    __syncthreads();
    int m = gcur[b]; if (m > PCAP) m = PCAP;
    for (int i = t; i < m; i += 1024) {
        unsigned int p = ebuf[(size_t)b * PCAP + i];
        int dl = p >> 16;
        int s = p & 0xFFFFu;
        int c = atomicAdd(&scnt[dl], 1);
        if (c < CAP) sbuf[dl * CAP + c] = (unsigned short)s;
    }
    __syncthreads();

    // phase 2: wave wv aggregates nodes [wv*NPW, min((wv+1)*NPW, BNODES))
    const int wv = t >> 6;
    const int l = t & 63;
    const int head = l >> 4;
    const int c0 = 2 * l;
    int nl0 = wv * NPW;
    int gn0 = dbase + nl0;
    const bool active = (nl0 < BNODES) && (gn0 < N_NODES);
    if (active) {
        int nl1 = nl0 + NPW; if (nl1 > BNODES) nl1 = BNODES;
        int gn1 = dbase + nl1; if (gn1 > N_NODES) gn1 = N_NODES;
        const float2 bias = *(const float2*)(b1 + c0);
        float pool0 = 0.f, pool1 = 0.f;
        int cur = batch[gn0];
        for (int n = gn0; n < gn1; n++) {
            int bb = batch[n];
            if (bb != cur) {                   // wave-uniform branch
                atomicAdd(&g[(size_t)cur * HC + c0], pool0);
                atomicAdd(&g[(size_t)cur * HC + c0 + 1], pool1);
                pool0 = pool1 = 0.f;
                cur = bb;
            }
            int nl = n - dbase;
            int c = scnt[nl]; if (c > CAP) c = CAP;
            float4 ad = *(const float4*)(a_d + (size_t)n * 4);
            const unsigned short* __restrict__ srow = &sbuf[nl * CAP];
            for (int i = l; i < c; i += 64) {  // weight fill (this wave only)
                int s = srow[i];
                float4 as = *(const float4*)(a_s + (size_t)s * 4);
                sWt[wv][0][i] = lrelu_exp(as.x + ad.x);
                sWt[wv][1][i] = lrelu_exp(as.y + ad.y);
                sWt[wv][2][i] = lrelu_exp(as.z + ad.z);
                sWt[wv][3][i] = lrelu_exp(as.w + ad.w);
            }
            __asm__ volatile("" ::: "memory"); // wave-coherent LDS
            const float* __restrict__ wrow = &sWt[wv][head][0];
            float acc0 = 0.f, acc1 = 0.f, dsum = 0.f;
            int i = 0;
            for (; i + 16 <= c; i += 16) {     // 16-edge interleave for MLP
                unsigned int u[16];
                float w[16];
#pragma unroll
                for (int q = 0; q < 16; q++) {
                    int sq = srow[i + q];
                    w[q] = wrow[i + q];
                    u[q] = *(const unsigned int*)(hb + (size_t)sq * HC + c0);
                }
#pragma unroll
                for (int q = 0; q < 16; q++) {
                    dsum += w[q];
                    acc0 += w[q] * __uint_as_float(u[q] << 16);
                    acc1 += w[q] * __uint_as_float(u[q] & 0xFFFF0000u);
                }
            }
            for (; i + 8 <= c; i += 8) {       // 8-edge tail
                unsigned int u[8];
                float w[8];
#pragma unroll
                for (int q = 0; q < 8; q++) {
                    int sq = srow[i + q];
                    w[q] = wrow[i + q];
                    u[q] = *(const unsigned int*)(hb + (size_t)sq * HC + c0);
                }
#pragma unroll
                for (int q = 0; q < 8; q++) {
                    dsum += w[q];
                    acc0 += w[q] * __uint_as_float(u[q] << 16);
                    acc1 += w[q] * __uint_as_float(u[q] & 0xFFFF0000u);
                }
            }
            for (; i < c; i++) {
                int s0 = srow[i];
                float w0 = wrow[i];
                unsigned int u0 = *(const unsigned int*)(hb + (size_t)s0 * HC + c0);
                dsum += w0;
                acc0 += w0 * __uint_as_float(u0 << 16);
                acc1 += w0 * __uint_as_float(u0 & 0xFFFF0000u);
            }
            __asm__ volatile("" ::: "memory");
            float inv = 1.f / (dsum + 1e-16f);
            float v0 = acc0 * inv + bias.x; v0 = v0 > 0.f ? v0 : (__expf(v0) - 1.f);
            float v1 = acc1 * inv + bias.y; v1 = v1 > 0.f ? v1 : (__expf(v1) - 1.f);
            pool0 += v0;
            pool1 += v1;
        }
        atomicAdd(&g[(size_t)cur * HC + c0], pool0);
        atomicAdd(&g[(size_t)cur * HC + c0 + 1], pool1);
    }

    // ---- last-block MLP (no fence: __syncthreads drains vmcnt) ----
    __syncthreads();
    if (t == 0) slast = (atomicAdd(ticket, 1) == NB - 1) ? 1 : 0;
    __syncthreads();
    if (!slast) return;

    float* sw1  = (float*)sbuf;            // [128][32] = 16 KB (sbuf dead)
    float* sg2  = &sWt[0][0][0];           // [32][128] = 16 KB (sWt dead)
    float* shid = sg2 + 32 * HC;           // [32][32]  =  4 KB
    for (int i = t; i < HC * HID; i += 1024) sw1[i] = lin1_w[i];
    __syncthreads();
    const int gl = t >> 5;                 // 0..31 graph-local
    const int h  = t & 31;                 // hidden idx
    for (int chunk = 0; chunk < B_GRAPHS / 32; chunk++) {   // 16 chunks
        int gbase = chunk * 32;
        for (int i = t; i < 32 * HC; i += 1024) {
            int gi = gbase + (i >> 7);
            sg2[i] = __hip_atomic_load(&g[(size_t)gi * HC + (i & 127)],
                                       __ATOMIC_RELAXED, __HIP_MEMORY_SCOPE_AGENT);
        }
        __syncthreads();
        float acc = lin1_b[h];
#pragma unroll 8
        for (int k = 0; k < HC; k++)
            acc += sg2[gl * HC + k] * sw1[k * HID + h];
        shid[gl * HID + h] = acc;
        __syncthreads();
        if (t < 32 * OUT_CH) {
            int gi2 = t >> 4, o = t & 15;
            float a2 = lin2_b[o];
#pragma unroll
            for (int k = 0; k < HID; k++)
                a2 += shid[gi2 * HID + k] * lin2_w[k * OUT_CH + o];
            out[(size_t)(gbase + gi2) * OUT_CH + o] = a2;
        }
        __syncthreads();                   // before next chunk overwrites
    }
}

extern "C" void kernel_launch(void* const* d_in, const int* in_sizes, int n_in,
                              void* d_out, int out_size, void* d_ws, size_t ws_size,
                              hipStream_t stream) {
    const float* x       = (const float*)d_in[0];
    const int*   ei      = (const int*)d_in[1];
    const int*   batch   = (const int*)d_in[2];
    const float* W1      = (const float*)d_in[3];
    const float* att_src = (const float*)d_in[4];
    const float* att_dst = (const float*)d_in[5];
    const float* b1      = (const float*)d_in[6];
    const float* lin1_w  = (const float*)d_in[7];
    const float* lin1_b  = (const float*)d_in[8];
    const float* lin2_w  = (const float*)d_in[9];
    const float* lin2_b  = (const float*)d_in[10];
    float* out = (float*)d_out;

    float* ws = (float*)d_ws;
    // layout (float-offsets into ws):
    unsigned short* hb   = (unsigned short*)ws;    // N*128 bf16 -> 3,200,000 floats
    float*  a_s      = ws + 3200000;               //   200,000
    float*  a_d      = ws + 3400000;               //   200,000
    unsigned int* ebuf = (unsigned int*)(ws + 3600000);     // NB*PCAP = 512*3552 = 1,818,624
    unsigned short* whiF = (unsigned short*)(ws + 5418624); // 16384 us = 8192 floats
    unsigned short* wloF = (unsigned short*)(ws + 5426816); // 16384 us = 8192 floats
    int*    gcur     = (int*)(ws + 5435008);       // 512 + ticket at [512]
    float*  g        = ws + 5436000;               //    65,536
    // total ~5.5M floats = 22 MB (same footprint as R15-25)

    k_prep<<<64, 256, 0, stream>>>(W1, whiF, wloF, gcur);
    k_fused<<<TOT_BLOCKS, 256, 0, stream>>>(
        x, whiF, wloF, att_src, att_dst, ei, hb, a_s, a_d, gcur, ebuf, g);
    k_aggB<<<NB, 1024, 0, stream>>>(ebuf, gcur, a_s, a_d, hb, b1, batch, g,
                                    gcur + NB, lin1_w, lin1_b, lin2_w, lin2_b, out);
}

// Round 13
// 191.342 us; speedup vs baseline: 1.3977x; 1.3977x over previous
//
#include <hip/hip_runtime.h>
#include <hip/hip_bf16.h>
#include <hip/hip_fp16.h>

#define N_NODES 50000
#define E_EDGES 1600000
#define IN_CH 128
#define HID 32
#define HEADS 4
#define HC (HEADS * HID)         // 128
#define OUT_CH 16
#define B_GRAPHS 512
#define NEG_SLOPE 0.2f
#define CAP 96                   // per-node capacity; deg = 1+Pois(32), P(>96)~1e-18
#define NB 512                   // coarse buckets (R15: 2 blocks/CU in k_aggB)
#define BNODES 98                // nodes per bucket (512*98 = 50176 >= 50000)
#define PCAP 3552                // per-bucket edge capacity (mean 3125 + 7.6 sd)
#define ACHUNK 4096              // edges per pass-A block
#define APART 391                // ceil(E_EDGES / ACHUNK)
#define ROWS_PB 64
#define GEMM_BLOCKS 782          // ceil(50000 / 64)
#define TOT_BLOCKS 1173          // APART + GEMM_BLOCKS, interleaved 1:2

// R20 LESSON: no __threadfence() on per-block paths (per-wave L2 writeback).
// R26 LESSON: serial single-block tail (ticket MLP) = ~90 µs on one CU —
// far worse than the ~15 µs launch it saves. Keep tiny dependent work as
// its own wide kernel. Fusion of the aggB->mlp boundary is CLOSED.
// R21 LESSON: source-level load prefetch gets compiler-canonicalized away.
// R22 LESSON: passA+gemm interleaved-in-one-kernel beats sequential ~7 µs.
// R23 LESSON: 8->16 outstanding gathers = no change — k_aggB issue-bound.
// R24 LESSON: readfirstlane on LDS values = per-value lgkmcnt waits. No.
// R25 LESSON: W-hi in LDS ~= W streamed (58 vs 60 µs) — swh bought nothing;
// R27 spends that LDS on occupancy instead (33->16.9 KB, 4->8 blocks/CU).

typedef short bfrag __attribute__((ext_vector_type(8)));   // 8 bf16 = 4 VGPR
typedef float facc  __attribute__((ext_vector_type(4)));   // MFMA 16x16 C/D

__device__ __forceinline__ unsigned short f2bf(float f) {
    unsigned int u = __float_as_uint(f);
    unsigned int r = (u + 0x7FFFu + ((u >> 16) & 1u)) >> 16;   // RNE
    return (unsigned short)r;
}

__device__ __forceinline__ float lrelu_exp(float v) {
    v = v > 0.f ? v : NEG_SLOPE * v;
    return __expf(v);
}

// split two fp32 into packed bf16 hi-pair and RNE lo-pair (R18-exact math)
__device__ __forceinline__ void split2(float a, float b,
                                       unsigned int& hi, unsigned int& lo) {
    unsigned int ua = __float_as_uint(a), ub = __float_as_uint(b);
    hi = (ua >> 16) | (ub & 0xFFFF0000u);
    float la = a - __uint_as_float(ua & 0xFFFF0000u);
    float lb = b - __uint_as_float(ub & 0xFFFF0000u);
    lo = (unsigned int)f2bf(la) | ((unsigned int)f2bf(lb) << 16);
}

// ---- K0: prep — W1 fp32 -> FRAGMENT-LINEAR bf16 hi/lo; zero gcur --------
// Layout whiF[((nt*4+kc)*64 + l)*8 + e]: a wave's B-frag load is lane l
// reading base + l*16B — one coalesced 1KB load (R19-proven).
__global__ __launch_bounds__(256) void k_prep(const float* __restrict__ W1,
                                              unsigned short* __restrict__ whiF,
                                              unsigned short* __restrict__ wloF,
                                              int* __restrict__ gcur) {
    int tid = blockIdx.x * 256 + threadIdx.x;      // grid 64 -> 16384
    if (tid < NB) gcur[tid] = 0;
    int e = tid & 7, l = (tid >> 3) & 63, q = tid >> 9;   // q = nt*4+kc
    int nt = q >> 2, kc = q & 3;
    int n = nt * 16 + (l & 15);
    int k = kc * 32 + (l >> 4) * 8 + e;
    float v = W1[k * 128 + n];
    unsigned int u = __float_as_uint(v);
    float lo_f = v - __uint_as_float(u & 0xFFFF0000u);  // exact residual
    whiF[tid] = (unsigned short)(u >> 16);              // truncated hi
    wloF[tid] = f2bf(lo_f);
}

// ---- K1: fused pass-A + split-bf16 MFMA GEMM, INTERLEAVED 1:2 ------------
// R27: LDS cut to 16.9 KB -> 8 blocks/CU (was 33 KB / 4). Both W halves
// streamed from L2 (R19-proven loop); x straight to A-frags (R25-proven);
// scores in-register via 16-lane shfl_xor over the D-layout; hb restashed
// as bf16 (identical f2bf bytes) with ONE barrier.
// Fragment layouts (gfx950 16x16x32): A: m=l&15, k=(l>>4)*8+e;
// B: n=l&15, k=(l>>4)*8+e; D: col=l&15, row=(l>>4)*4+r [R18-verified].
__global__ __launch_bounds__(256) void k_fused(const float* __restrict__ x,
                                               const unsigned short* __restrict__ whiF,
                                               const unsigned short* __restrict__ wloF,
                                               const float* __restrict__ att_src,
                                               const float* __restrict__ att_dst,
                                               const int* __restrict__ ei,
                                               unsigned short* __restrict__ hb,
                                               float* __restrict__ a_s,
                                               float* __restrict__ a_d,
                                               int* __restrict__ gcur,
                                               unsigned int* __restrict__ ebuf,
                                               float* __restrict__ g) {
    __shared__ float smem[4224];           // 16896 B: pass-A 16384 / sHu[64][132] bf16
    const int t = threadIdx.x;
    const int bI = blockIdx.x;

    if (bI % 3 == 0) {
        // ---- pass A with per-wave sub-histograms (16 KB of smem) ----
        const int ablk = bI / 3;           // 0..390
        int* scnt = (int*)smem;            // [4][NB] = 8 KB
        int* sbase = scnt + 4 * NB;        // [4][NB] = 8 KB
        const int wv = t >> 6;
        const int e0 = ablk * ACHUNK;
        int e1 = e0 + ACHUNK; if (e1 > E_EDGES) e1 = E_EDGES;
        for (int i = t; i < 4 * NB; i += 256) scnt[i] = 0;
        __syncthreads();
        const int* __restrict__ dstp = ei + E_EDGES;
        for (int e = e0 + t; e < e1; e += 256) {
            int d = dstp[e];
            atomicAdd(&scnt[wv * NB + d / BNODES], 1);
        }
        __syncthreads();
        for (int i = t; i < NB; i += 256) {
            int c0 = scnt[0 * NB + i], c1 = scnt[1 * NB + i];
            int c2 = scnt[2 * NB + i], c3 = scnt[3 * NB + i];
            int base = atomicAdd(&gcur[i], c0 + c1 + c2 + c3);
            sbase[0 * NB + i] = base;
            sbase[1 * NB + i] = base + c0;
            sbase[2 * NB + i] = base + c0 + c1;
            sbase[3 * NB + i] = base + c0 + c1 + c2;
            scnt[0 * NB + i] = 0; scnt[1 * NB + i] = 0;
            scnt[2 * NB + i] = 0; scnt[3 * NB + i] = 0;
        }
        __syncthreads();
        for (int e = e0 + t; e < e1; e += 256) {
            int d = dstp[e];
            int s = ei[e];
            int b = d / BNODES;
            int dl = d - b * BNODES;
            int pos = sbase[wv * NB + b] + atomicAdd(&scnt[wv * NB + b], 1);
            if (pos < PCAP)
                ebuf[(size_t)b * PCAP + pos] = ((unsigned int)dl << 16) | (unsigned int)s;
        }
        return;                            // uniform exit
    }

    // ---- GEMM part ----
    const int bid = bI - bI / 3 - 1;       // 0..781
    const int n0 = bid * ROWS_PB;

    int gt = bid * 256 + t;
    if (gt < B_GRAPHS * HC) g[gt] = 0.f;   // fused g-zero

    const int wv = t >> 6, l = t & 63;
    const int lm = l & 15, lk = l >> 4;
    const int band = wv * 16;              // wave's 16-row band

    // A-frags straight from global (R25-proven)
    bfrag ahi[4], alo[4];
    {
        int row = n0 + band + lm;
        bool valid = row < N_NODES;
        const float* xr = x + (size_t)(valid ? row : 0) * IN_CH;
#pragma unroll
        for (int kc = 0; kc < 4; kc++) {
            float4 v0 = *(const float4*)(xr + kc * 32 + lk * 8);
            float4 v1 = *(const float4*)(xr + kc * 32 + lk * 8 + 4);
            if (!valid) { v0 = make_float4(0.f,0.f,0.f,0.f); v1 = v0; }
            union { bfrag f; unsigned int u[4]; } H, L;
            split2(v0.x, v0.y, H.u[0], L.u[0]);
            split2(v0.z, v0.w, H.u[1], L.u[1]);
            split2(v1.x, v1.y, H.u[2], L.u[2]);
            split2(v1.z, v1.w, H.u[3], L.u[3]);
            ahi[kc] = H.f; alo[kc] = L.f;
        }
    }

    facc acc[8];
#pragma unroll
    for (int nt = 0; nt < 8; nt++) acc[nt] = (facc){0.f, 0.f, 0.f, 0.f};

    {
        const int lb = l * 8;              // lane offset within each 1KB frag slab
#pragma unroll
        for (int q = 0; q < 32; q++) {     // q = nt*4+kc (R19-proven loop)
            bfrag bhv = *(const bfrag*)(whiF + q * 512 + lb);
            bfrag blv = *(const bfrag*)(wloF + q * 512 + lb);
            const int nt = q >> 2, kc = q & 3;
            acc[nt] = __builtin_amdgcn_mfma_f32_16x16x32_bf16(ahi[kc], bhv, acc[nt], 0, 0, 0);
            acc[nt] = __builtin_amdgcn_mfma_f32_16x16x32_bf16(alo[kc], bhv, acc[nt], 0, 0, 0);
            acc[nt] = __builtin_amdgcn_mfma_f32_16x16x32_bf16(ahi[kc], blv, acc[nt], 0, 0, 0);
        }
    }

    // scores in-register (fp32, from accs): row band+lk*4+r is held by the
    // 16 lanes sharing lk (lane lm owns cols ≡ lm mod 16). Per-head partial
    // over nt=2h,2h+1 then 4-step butterfly across the 16-lane group.
    {
        float asv[8], adv[8];
#pragma unroll
        for (int nt = 0; nt < 8; nt++) {
            asv[nt] = att_src[nt * 16 + lm];
            adv[nt] = att_dst[nt * 16 + lm];
        }
#pragma unroll
        for (int r = 0; r < 4; r++) {
            float s[4], d4[4];
#pragma unroll
            for (int h = 0; h < 4; h++) {
                s[h]  = acc[2*h][r] * asv[2*h] + acc[2*h+1][r] * asv[2*h+1];
                d4[h] = acc[2*h][r] * adv[2*h] + acc[2*h+1][r] * adv[2*h+1];
            }
#pragma unroll
            for (int m = 1; m < 16; m <<= 1) {
#pragma unroll
                for (int h = 0; h < 4; h++) {
                    s[h]  += __shfl_xor(s[h], m);
                    d4[h] += __shfl_xor(d4[h], m);
                }
            }
            int n = n0 + band + lk * 4 + r;
            if (lm == 0 && n < N_NODES) {
                *(float4*)(a_s + (size_t)n * 4) = make_float4(s[0], s[1], s[2], s[3]);
                *(float4*)(a_d + (size_t)n * 4) = make_float4(d4[0], d4[1], d4[2], d4[3]);
            }
        }
    }

    // bf16 restash (identical f2bf bytes as direct store) -> ONE barrier ->
    // coalesced ushort4 hb rows. [64][132]: row stride 264 B (8-aligned).
    unsigned short* sHu = (unsigned short*)smem;
#pragma unroll
    for (int nt = 0; nt < 8; nt++) {
#pragma unroll
        for (int r = 0; r < 4; r++)
            sHu[(band + lk * 4 + r) * 132 + nt * 16 + lm] = f2bf(acc[nt][r]);
    }
    __syncthreads();
    for (int i = t; i < 64 * 32; i += 256) {
        int row = i >> 5, c4 = i & 31;
        int n = n0 + row;
        if (n < N_NODES) {
            ushort4 o = *(const ushort4*)&sHu[row * 132 + c4 * 4];
            *(ushort4*)&hb[(size_t)n * HC + c4 * 4] = o;
        }
    }
}

// ---- K2: fused pass-B + aggregate + pool (one 1024-thr block / bucket) --
// R23-exact. 16-edge unrolled gather; NB=512, 2 blocks/CU, 32 waves.
#define NPW 7                     // ceil(BNODES / 16); waves 14,15 idle
__global__ __launch_bounds__(1024) void k_aggB(const unsigned int* __restrict__ ebuf,
                                               const int* __restrict__ gcur,
                                               const float* __restrict__ a_s,
                                               const float* __restrict__ a_d,
                                               const unsigned short* __restrict__ hb,
                                               const float* __restrict__ b1,
                                               const int* __restrict__ batch,
                                               float* __restrict__ g) {
    __shared__ unsigned short sbuf[BNODES * CAP];   // 18816 B
    __shared__ int scnt[BNODES];                    //   392 B
    __shared__ float sWt[16][4][97];                // 24832 B  (~44 KB total)
    const int t = threadIdx.x;
    const int b = blockIdx.x;
    const int dbase = b * BNODES;

    // phase 1: self-loop seed + LDS scatter of this bucket's edges
    for (int i = t; i < BNODES; i += 1024) {
        int d = dbase + i;
        scnt[i] = (d < N_NODES) ? 1 : 0;
        sbuf[i * CAP] = (unsigned short)d;
    }
    __syncthreads();
    int m = gcur[b]; if (m > PCAP) m = PCAP;
    for (int i = t; i < m; i += 1024) {
        unsigned int p = ebuf[(size_t)b * PCAP + i];
        int dl = p >> 16;
        int s = p & 0xFFFFu;
        int c = atomicAdd(&scnt[dl], 1);
        if (c < CAP) sbuf[dl * CAP + c] = (unsigned short)s;
    }
    __syncthreads();

    // phase 2: wave wv aggregates nodes [wv*NPW, min((wv+1)*NPW, BNODES))
    const int wv = t >> 6;
    const int l = t & 63;
    const int head = l >> 4;
    const int c0 = 2 * l;
    int nl0 = wv * NPW;
    if (nl0 >= BNODES) return;             // waves beyond bucket: uniform exit
    int nl1 = nl0 + NPW; if (nl1 > BNODES) nl1 = BNODES;
    int gn0 = dbase + nl0;
    if (gn0 >= N_NODES) return;
    int gn1 = dbase + nl1; if (gn1 > N_NODES) gn1 = N_NODES;
    const float2 bias = *(const float2*)(b1 + c0);
    float pool0 = 0.f, pool1 = 0.f;
    int cur = batch[gn0];
    for (int n = gn0; n < gn1; n++) {
        int bb = batch[n];
        if (bb != cur) {                   // wave-uniform branch
            atomicAdd(&g[(size_t)cur * HC + c0], pool0);
            atomicAdd(&g[(size_t)cur * HC + c0 + 1], pool1);
            pool0 = pool1 = 0.f;
            cur = bb;
        }
        int nl = n - dbase;
        int c = scnt[nl]; if (c > CAP) c = CAP;
        float4 ad = *(const float4*)(a_d + (size_t)n * 4);
        const unsigned short* __restrict__ srow = &sbuf[nl * CAP];
        for (int i = l; i < c; i += 64) {  // weight fill (this wave only)
            int s = srow[i];
            float4 as = *(const float4*)(a_s + (size_t)s * 4);
            sWt[wv][0][i] = lrelu_exp(as.x + ad.x);
            sWt[wv][1][i] = lrelu_exp(as.y + ad.y);
            sWt[wv][2][i] = lrelu_exp(as.z + ad.z);
            sWt[wv][3][i] = lrelu_exp(as.w + ad.w);
        }
        __asm__ volatile("" ::: "memory"); // wave-coherent LDS
        const float* __restrict__ wrow = &sWt[wv][head][0];
        float acc0 = 0.f, acc1 = 0.f, dsum = 0.f;
        int i = 0;
        for (; i + 16 <= c; i += 16) {     // 16-edge interleave for MLP
            unsigned int u[16];
            float w[16];
#pragma unroll
            for (int q = 0; q < 16; q++) {
                int sq = srow[i + q];
                w[q] = wrow[i + q];
                u[q] = *(const unsigned int*)(hb + (size_t)sq * HC + c0);
            }
#pragma unroll
            for (int q = 0; q < 16; q++) {
                dsum += w[q];
                acc0 += w[q] * __uint_as_float(u[q] << 16);
                acc1 += w[q] * __uint_as_float(u[q] & 0xFFFF0000u);
            }
        }
        for (; i + 8 <= c; i += 8) {       // 8-edge tail
            unsigned int u[8];
            float w[8];
#pragma unroll
            for (int q = 0; q < 8; q++) {
                int sq = srow[i + q];
                w[q] = wrow[i + q];
                u[q] = *(const unsigned int*)(hb + (size_t)sq * HC + c0);
            }
#pragma unroll
            for (int q = 0; q < 8; q++) {
                dsum += w[q];
                acc0 += w[q] * __uint_as_float(u[q] << 16);
                acc1 += w[q] * __uint_as_float(u[q] & 0xFFFF0000u);
            }
        }
        for (; i < c; i++) {
            int s0 = srow[i];
            float w0 = wrow[i];
            unsigned int u0 = *(const unsigned int*)(hb + (size_t)s0 * HC + c0);
            dsum += w0;
            acc0 += w0 * __uint_as_float(u0 << 16);
            acc1 += w0 * __uint_as_float(u0 & 0xFFFF0000u);
        }
        __asm__ volatile("" ::: "memory");
        float inv = 1.f / (dsum + 1e-16f);
        float v0 = acc0 * inv + bias.x; v0 = v0 > 0.f ? v0 : (__expf(v0) - 1.f);
        float v1 = acc1 * inv + bias.y; v1 = v1 > 0.f ? v1 : (__expf(v1) - 1.f);
        pool0 += v0;
        pool1 += v1;
    }
    atomicAdd(&g[(size_t)cur * HC + c0], pool0);
    atomicAdd(&g[(size_t)cur * HC + c0 + 1], pool1);
}

// ---------------- K3: tiny 2-layer MLP on pooled graphs ------------------
__global__ __launch_bounds__(64) void k_mlp(const float* __restrict__ g,
                                            const float* __restrict__ w1,
                                            const float* __restrict__ bb1,
                                            const float* __restrict__ w2,
                                            const float* __restrict__ bb2,
                                            float* __restrict__ out) {
    __shared__ float sg[HC];
    __shared__ float st[HID];
    int b = blockIdx.x;
    int t = threadIdx.x;   // 64
    sg[t]      = g[(size_t)b * HC + t];
    sg[t + 64] = g[(size_t)b * HC + 64 + t];
    __syncthreads();
    if (t < HID) {
        float acc = bb1[t];
#pragma unroll 8
        for (int k = 0; k < HC; k++) acc += sg[k] * w1[(size_t)k * HID + t];
        st[t] = acc;
    }
    __syncthreads();
    if (t < OUT_CH) {
        float acc = bb2[t];
#pragma unroll
        for (int k = 0; k < HID; k++) acc += st[k] * w2[(size_t)k * OUT_CH + t];
        out[(size_t)b * OUT_CH + t] = acc;
    }
}

extern "C" void kernel_launch(void* const* d_in, const int* in_sizes, int n_in,
                              void* d_out, int out_size, void* d_ws, size_t ws_size,
                              hipStream_t stream) {
    const float* x       = (const float*)d_in[0];
    const int*   ei      = (const int*)d_in[1];
    const int*   batch   = (const int*)d_in[2];
    const float* W1      = (const float*)d_in[3];
    const float* att_src = (const float*)d_in[4];
    const float* att_dst = (const float*)d_in[5];
    const float* b1      = (const float*)d_in[6];
    const float* lin1_w  = (const float*)d_in[7];
    const float* lin1_b  = (const float*)d_in[8];
    const float* lin2_w  = (const float*)d_in[9];
    const float* lin2_b  = (const float*)d_in[10];
    float* out = (float*)d_out;

    float* ws = (float*)d_ws;
    // layout (float-offsets into ws):
    unsigned short* hb   = (unsigned short*)ws;    // N*128 bf16 -> 3,200,000 floats
    float*  a_s      = ws + 3200000;               //   200,000
    float*  a_d      = ws + 3400000;               //   200,000
    unsigned int* ebuf = (unsigned int*)(ws + 3600000);     // NB*PCAP = 512*3552 = 1,818,624
    unsigned short* whiF = (unsigned short*)(ws + 5418624); // 16384 us = 8192 floats
    unsigned short* wloF = (unsigned short*)(ws + 5426816); // 16384 us = 8192 floats
    int*    gcur     = (int*)(ws + 5435008);       //       512
    float*  g        = ws + 5436000;               //    65,536
    // total ~5.5M floats = 22 MB (same footprint as R15-26)

    k_prep<<<64, 256, 0, stream>>>(W1, whiF, wloF, gcur);
    k_fused<<<TOT_BLOCKS, 256, 0, stream>>>(
        x, whiF, wloF, att_src, att_dst, ei, hb, a_s, a_d, gcur, ebuf, g);
    k_aggB<<<NB, 1024, 0, stream>>>(ebuf, gcur, a_s, a_d, hb, b1, batch, g);
    k_mlp<<<B_GRAPHS, 64, 0, stream>>>(g, lin1_w, lin1_b, lin2_w, lin2_b, out);
}

// Round 14
// 189.995 us; speedup vs baseline: 1.4076x; 1.0071x over previous
//
#include <hip/hip_runtime.h>
#include <hip/hip_bf16.h>
#include <hip/hip_fp16.h>

#define N_NODES 50000
#define E_EDGES 1600000
#define IN_CH 128
#define HID 32
#define HEADS 4
#define HC (HEADS * HID)         // 128
#define OUT_CH 16
#define B_GRAPHS 512
#define NEG_SLOPE 0.2f
#define CAP 96                   // per-node capacity; deg = 1+Pois(32), P(>96)~1e-18
#define NB 512                   // coarse buckets (R15: 2 blocks/CU in k_aggB)
#define BNODES 98                // nodes per bucket (512*98 = 50176 >= 50000)
#define PCAP 3552                // per-bucket edge capacity (mean 3125 + 7.6 sd)
#define ACHUNK 8192              // edges per pass-A block (R28: 4096->8192)
#define APART 196                // ceil(E_EDGES / ACHUNK)
#define ROWS_PB 64
#define GEMM_BLOCKS 782          // ceil(50000 / 64)
#define TOT_BLOCKS 978           // APART + GEMM_BLOCKS, interleaved 1:4

// R20 LESSON: no __threadfence() on per-block paths (per-wave L2 writeback).
// R26 LESSON: serial single-block tail (ticket MLP) = ~90 µs on one CU.
// aggB->mlp fusion is CLOSED (two mechanisms tried, both lost).
// R21 LESSON: source-level load prefetch gets compiler-canonicalized away.
// R22 LESSON: passA+gemm interleaved-in-one-kernel beats sequential ~7 µs.
// R23 LESSON: 8->16 outstanding gathers = no change — k_aggB issue-bound.
// R24 LESSON: readfirstlane on LDS values = per-value lgkmcnt waits. No.
// R25/R27 LESSON: W-in-LDS ~= W-streamed; occupancy 4->8 blk/CU neutral —
// GEMM q-loop chain is insensitive to both. Pass-A chunk overhead is the
// remaining k_fused lever (R28).
// k_aggB floor: 422 MB wave-coalesced random hb gathers @ ~3 TB/s L2-miss
// path — structural at bf16 row-major (layout changes amplify the gather).

typedef short bfrag __attribute__((ext_vector_type(8)));   // 8 bf16 = 4 VGPR
typedef float facc  __attribute__((ext_vector_type(4)));   // MFMA 16x16 C/D

__device__ __forceinline__ unsigned short f2bf(float f) {
    unsigned int u = __float_as_uint(f);
    unsigned int r = (u + 0x7FFFu + ((u >> 16) & 1u)) >> 16;   // RNE
    return (unsigned short)r;
}

__device__ __forceinline__ float lrelu_exp(float v) {
    v = v > 0.f ? v : NEG_SLOPE * v;
    return __expf(v);
}

// split two fp32 into packed bf16 hi-pair and RNE lo-pair (R18-exact math)
__device__ __forceinline__ void split2(float a, float b,
                                       unsigned int& hi, unsigned int& lo) {
    unsigned int ua = __float_as_uint(a), ub = __float_as_uint(b);
    hi = (ua >> 16) | (ub & 0xFFFF0000u);
    float la = a - __uint_as_float(ua & 0xFFFF0000u);
    float lb = b - __uint_as_float(ub & 0xFFFF0000u);
    lo = (unsigned int)f2bf(la) | ((unsigned int)f2bf(lb) << 16);
}

// ---- K0: prep — W1 fp32 -> FRAGMENT-LINEAR bf16 hi/lo; zero gcur --------
__global__ __launch_bounds__(256) void k_prep(const float* __restrict__ W1,
                                              unsigned short* __restrict__ whiF,
                                              unsigned short* __restrict__ wloF,
                                              int* __restrict__ gcur) {
    int tid = blockIdx.x * 256 + threadIdx.x;      // grid 64 -> 16384
    if (tid < NB) gcur[tid] = 0;
    int e = tid & 7, l = (tid >> 3) & 63, q = tid >> 9;   // q = nt*4+kc
    int nt = q >> 2, kc = q & 3;
    int n = nt * 16 + (l & 15);
    int k = kc * 32 + (l >> 4) * 8 + e;
    float v = W1[k * 128 + n];
    unsigned int u = __float_as_uint(v);
    float lo_f = v - __uint_as_float(u & 0xFFFF0000u);  // exact residual
    whiF[tid] = (unsigned short)(u >> 16);              // truncated hi
    wloF[tid] = f2bf(lo_f);
}

// ---- K1: fused pass-A + split-bf16 MFMA GEMM, INTERLEAVED 1:4 ------------
// R27 GEMM structure (16.9 KB LDS, 8 blk/CU, W streamed, in-reg scores).
// R28: ACHUNK 8192 — halves pass-A per-chunk overhead (barriers, prefix
// atomics, scnt zeroing).
// Fragment layouts (gfx950 16x16x32): A: m=l&15, k=(l>>4)*8+e;
// B: n=l&15, k=(l>>4)*8+e; D: col=l&15, row=(l>>4)*4+r [R18-verified].
__global__ __launch_bounds__(256) void k_fused(const float* __restrict__ x,
                                               const unsigned short* __restrict__ whiF,
                                               const unsigned short* __restrict__ wloF,
                                               const float* __restrict__ att_src,
                                               const float* __restrict__ att_dst,
                                               const int* __restrict__ ei,
                                               unsigned short* __restrict__ hb,
                                               float* __restrict__ a_s,
                                               float* __restrict__ a_d,
                                               int* __restrict__ gcur,
                                               unsigned int* __restrict__ ebuf,
                                               float* __restrict__ g) {
    __shared__ float smem[4224];           // 16896 B: pass-A 16384 / sHu[64][132] bf16
    const int t = threadIdx.x;
    const int bI = blockIdx.x;

    if (bI % 5 == 0) {
        // ---- pass A with per-wave sub-histograms (16 KB of smem) ----
        const int ablk = bI / 5;           // 0..195
        int* scnt = (int*)smem;            // [4][NB] = 8 KB
        int* sbase = scnt + 4 * NB;        // [4][NB] = 8 KB
        const int wv = t >> 6;
        const int e0 = ablk * ACHUNK;
        int e1 = e0 + ACHUNK; if (e1 > E_EDGES) e1 = E_EDGES;
        for (int i = t; i < 4 * NB; i += 256) scnt[i] = 0;
        __syncthreads();
        const int* __restrict__ dstp = ei + E_EDGES;
        for (int e = e0 + t; e < e1; e += 256) {
            int d = dstp[e];
            atomicAdd(&scnt[wv * NB + d / BNODES], 1);
        }
        __syncthreads();
        for (int i = t; i < NB; i += 256) {
            int c0 = scnt[0 * NB + i], c1 = scnt[1 * NB + i];
            int c2 = scnt[2 * NB + i], c3 = scnt[3 * NB + i];
            int base = atomicAdd(&gcur[i], c0 + c1 + c2 + c3);
            sbase[0 * NB + i] = base;
            sbase[1 * NB + i] = base + c0;
            sbase[2 * NB + i] = base + c0 + c1;
            sbase[3 * NB + i] = base + c0 + c1 + c2;
            scnt[0 * NB + i] = 0; scnt[1 * NB + i] = 0;
            scnt[2 * NB + i] = 0; scnt[3 * NB + i] = 0;
        }
        __syncthreads();
        for (int e = e0 + t; e < e1; e += 256) {
            int d = dstp[e];
            int s = ei[e];
            int b = d / BNODES;
            int dl = d - b * BNODES;
            int pos = sbase[wv * NB + b] + atomicAdd(&scnt[wv * NB + b], 1);
            if (pos < PCAP)
                ebuf[(size_t)b * PCAP + pos] = ((unsigned int)dl << 16) | (unsigned int)s;
        }
        return;                            // uniform exit
    }

    // ---- GEMM part (R27-exact) ----
    const int bid = bI - bI / 5 - 1;       // 0..781
    const int n0 = bid * ROWS_PB;

    int gt = bid * 256 + t;
    if (gt < B_GRAPHS * HC) g[gt] = 0.f;   // fused g-zero

    const int wv = t >> 6, l = t & 63;
    const int lm = l & 15, lk = l >> 4;
    const int band = wv * 16;              // wave's 16-row band

    // A-frags straight from global (R25-proven)
    bfrag ahi[4], alo[4];
    {
        int row = n0 + band + lm;
        bool valid = row < N_NODES;
        const float* xr = x + (size_t)(valid ? row : 0) * IN_CH;
#pragma unroll
        for (int kc = 0; kc < 4; kc++) {
            float4 v0 = *(const float4*)(xr + kc * 32 + lk * 8);
            float4 v1 = *(const float4*)(xr + kc * 32 + lk * 8 + 4);
            if (!valid) { v0 = make_float4(0.f,0.f,0.f,0.f); v1 = v0; }
            union { bfrag f; unsigned int u[4]; } H, L;
            split2(v0.x, v0.y, H.u[0], L.u[0]);
            split2(v0.z, v0.w, H.u[1], L.u[1]);
            split2(v1.x, v1.y, H.u[2], L.u[2]);
            split2(v1.z, v1.w, H.u[3], L.u[3]);
            ahi[kc] = H.f; alo[kc] = L.f;
        }
    }

    facc acc[8];
#pragma unroll
    for (int nt = 0; nt < 8; nt++) acc[nt] = (facc){0.f, 0.f, 0.f, 0.f};

    {
        const int lb = l * 8;              // lane offset within each 1KB frag slab
#pragma unroll
        for (int q = 0; q < 32; q++) {     // q = nt*4+kc (R19-proven loop)
            bfrag bhv = *(const bfrag*)(whiF + q * 512 + lb);
            bfrag blv = *(const bfrag*)(wloF + q * 512 + lb);
            const int nt = q >> 2, kc = q & 3;
            acc[nt] = __builtin_amdgcn_mfma_f32_16x16x32_bf16(ahi[kc], bhv, acc[nt], 0, 0, 0);
            acc[nt] = __builtin_amdgcn_mfma_f32_16x16x32_bf16(alo[kc], bhv, acc[nt], 0, 0, 0);
            acc[nt] = __builtin_amdgcn_mfma_f32_16x16x32_bf16(ahi[kc], blv, acc[nt], 0, 0, 0);
        }
    }

    // scores in-register (fp32, from accs): 16-lane butterfly per head pair
    {
        float asv[8], adv[8];
#pragma unroll
        for (int nt = 0; nt < 8; nt++) {
            asv[nt] = att_src[nt * 16 + lm];
            adv[nt] = att_dst[nt * 16 + lm];
        }
#pragma unroll
        for (int r = 0; r < 4; r++) {
            float s[4], d4[4];
#pragma unroll
            for (int h = 0; h < 4; h++) {
                s[h]  = acc[2*h][r] * asv[2*h] + acc[2*h+1][r] * asv[2*h+1];
                d4[h] = acc[2*h][r] * adv[2*h] + acc[2*h+1][r] * adv[2*h+1];
            }
#pragma unroll
            for (int m = 1; m < 16; m <<= 1) {
#pragma unroll
                for (int h = 0; h < 4; h++) {
                    s[h]  += __shfl_xor(s[h], m);
                    d4[h] += __shfl_xor(d4[h], m);
                }
            }
            int n = n0 + band + lk * 4 + r;
            if (lm == 0 && n < N_NODES) {
                *(float4*)(a_s + (size_t)n * 4) = make_float4(s[0], s[1], s[2], s[3]);
                *(float4*)(a_d + (size_t)n * 4) = make_float4(d4[0], d4[1], d4[2], d4[3]);
            }
        }
    }

    // bf16 restash (identical f2bf bytes) -> ONE barrier -> coalesced rows
    unsigned short* sHu = (unsigned short*)smem;
#pragma unroll
    for (int nt = 0; nt < 8; nt++) {
#pragma unroll
        for (int r = 0; r < 4; r++)
            sHu[(band + lk * 4 + r) * 132 + nt * 16 + lm] = f2bf(acc[nt][r]);
    }
    __syncthreads();
    for (int i = t; i < 64 * 32; i += 256) {
        int row = i >> 5, c4 = i & 31;
        int n = n0 + row;
        if (n < N_NODES) {
            ushort4 o = *(const ushort4*)&sHu[row * 132 + c4 * 4];
            *(ushort4*)&hb[(size_t)n * HC + c4 * 4] = o;
        }
    }
}

// ---- K2: fused pass-B + aggregate + pool (one 1024-thr block / bucket) --
// R23-exact gather; R28: phase-1 ebuf replay vectorized uint2 (PCAP even).
#define NPW 7                     // ceil(BNODES / 16); waves 14,15 idle
__global__ __launch_bounds__(1024) void k_aggB(const unsigned int* __restrict__ ebuf,
                                               const int* __restrict__ gcur,
                                               const float* __restrict__ a_s,
                                               const float* __restrict__ a_d,
                                               const unsigned short* __restrict__ hb,
                                               const float* __restrict__ b1,
                                               const int* __restrict__ batch,
                                               float* __restrict__ g) {
    __shared__ unsigned short sbuf[BNODES * CAP];   // 18816 B
    __shared__ int scnt[BNODES];                    //   392 B
    __shared__ float sWt[16][4][97];                // 24832 B  (~44 KB total)
    const int t = threadIdx.x;
    const int b = blockIdx.x;
    const int dbase = b * BNODES;

    // phase 1: self-loop seed + LDS scatter of this bucket's edges
    for (int i = t; i < BNODES; i += 1024) {
        int d = dbase + i;
        scnt[i] = (d < N_NODES) ? 1 : 0;
        sbuf[i * CAP] = (unsigned short)d;
    }
    __syncthreads();
    int m = gcur[b]; if (m > PCAP) m = PCAP;
    {
        int m2 = m & ~1;
        const unsigned int* __restrict__ ebb = ebuf + (size_t)b * PCAP;
        for (int i = 2 * t; i < m2; i += 2048) {
            uint2 pp = *(const uint2*)&ebb[i];
            int dl = pp.x >> 16, s = pp.x & 0xFFFFu;
            int c = atomicAdd(&scnt[dl], 1);
            if (c < CAP) sbuf[dl * CAP + c] = (unsigned short)s;
            dl = pp.y >> 16; s = pp.y & 0xFFFFu;
            c = atomicAdd(&scnt[dl], 1);
            if (c < CAP) sbuf[dl * CAP + c] = (unsigned short)s;
        }
        if ((m & 1) && t == 0) {
            unsigned int p = ebb[m - 1];
            int dl = p >> 16, s = p & 0xFFFFu;
            int c = atomicAdd(&scnt[dl], 1);
            if (c < CAP) sbuf[dl * CAP + c] = (unsigned short)s;
        }
    }
    __syncthreads();

    // phase 2: wave wv aggregates nodes [wv*NPW, min((wv+1)*NPW, BNODES))
    const int wv = t >> 6;
    const int l = t & 63;
    const int head = l >> 4;
    const int c0 = 2 * l;
    int nl0 = wv * NPW;
    if (nl0 >= BNODES) return;             // waves beyond bucket: uniform exit
    int nl1 = nl0 + NPW; if (nl1 > BNODES) nl1 = BNODES;
    int gn0 = dbase + nl0;
    if (gn0 >= N_NODES) return;
    int gn1 = dbase + nl1; if (gn1 > N_NODES) gn1 = N_NODES;
    const float2 bias = *(const float2*)(b1 + c0);
    float pool0 = 0.f, pool1 = 0.f;
    int cur = batch[gn0];
    for (int n = gn0; n < gn1; n++) {
        int bb = batch[n];
        if (bb != cur) {                   // wave-uniform branch
            atomicAdd(&g[(size_t)cur * HC + c0], pool0);
            atomicAdd(&g[(size_t)cur * HC + c0 + 1], pool1);
            pool0 = pool1 = 0.f;
            cur = bb;
        }
        int nl = n - dbase;
        int c = scnt[nl]; if (c > CAP) c = CAP;
        float4 ad = *(const float4*)(a_d + (size_t)n * 4);
        const unsigned short* __restrict__ srow = &sbuf[nl * CAP];
        for (int i = l; i < c; i += 64) {  // weight fill (this wave only)
            int s = srow[i];
            float4 as = *(const float4*)(a_s + (size_t)s * 4);
            sWt[wv][0][i] = lrelu_exp(as.x + ad.x);
            sWt[wv][1][i] = lrelu_exp(as.y + ad.y);
            sWt[wv][2][i] = lrelu_exp(as.z + ad.z);
            sWt[wv][3][i] = lrelu_exp(as.w + ad.w);
        }
        __asm__ volatile("" ::: "memory"); // wave-coherent LDS
        const float* __restrict__ wrow = &sWt[wv][head][0];
        float acc0 = 0.f, acc1 = 0.f, dsum = 0.f;
        int i = 0;
        for (; i + 16 <= c; i += 16) {     // 16-edge interleave for MLP
            unsigned int u[16];
            float w[16];
#pragma unroll
            for (int q = 0; q < 16; q++) {
                int sq = srow[i + q];
                w[q] = wrow[i + q];
                u[q] = *(const unsigned int*)(hb + (size_t)sq * HC + c0);
            }
#pragma unroll
            for (int q = 0; q < 16; q++) {
                dsum += w[q];
                acc0 += w[q] * __uint_as_float(u[q] << 16);
                acc1 += w[q] * __uint_as_float(u[q] & 0xFFFF0000u);
            }
        }
        for (; i + 8 <= c; i += 8) {       // 8-edge tail
            unsigned int u[8];
            float w[8];
#pragma unroll
            for (int q = 0; q < 8; q++) {
                int sq = srow[i + q];
                w[q] = wrow[i + q];
                u[q] = *(const unsigned int*)(hb + (size_t)sq * HC + c0);
            }
#pragma unroll
            for (int q = 0; q < 8; q++) {
                dsum += w[q];
                acc0 += w[q] * __uint_as_float(u[q] << 16);
                acc1 += w[q] * __uint_as_float(u[q] & 0xFFFF0000u);
            }
        }
        for (; i < c; i++) {
            int s0 = srow[i];
            float w0 = wrow[i];
            unsigned int u0 = *(const unsigned int*)(hb + (size_t)s0 * HC + c0);
            dsum += w0;
            acc0 += w0 * __uint_as_float(u0 << 16);
            acc1 += w0 * __uint_as_float(u0 & 0xFFFF0000u);
        }
        __asm__ volatile("" ::: "memory");
        float inv = 1.f / (dsum + 1e-16f);
        float v0 = acc0 * inv + bias.x; v0 = v0 > 0.f ? v0 : (__expf(v0) - 1.f);
        float v1 = acc1 * inv + bias.y; v1 = v1 > 0.f ? v1 : (__expf(v1) - 1.f);
        pool0 += v0;
        pool1 += v1;
    }
    atomicAdd(&g[(size_t)cur * HC + c0], pool0);
    atomicAdd(&g[(size_t)cur * HC + c0 + 1], pool1);
}

// ---------------- K3: tiny 2-layer MLP on pooled graphs ------------------
__global__ __launch_bounds__(64) void k_mlp(const float* __restrict__ g,
                                            const float* __restrict__ w1,
                                            const float* __restrict__ bb1,
                                            const float* __restrict__ w2,
                                            const float* __restrict__ bb2,
                                            float* __restrict__ out) {
    __shared__ float sg[HC];
    __shared__ float st[HID];
    int b = blockIdx.x;
    int t = threadIdx.x;   // 64
    sg[t]      = g[(size_t)b * HC + t];
    sg[t + 64] = g[(size_t)b * HC + 64 + t];
    __syncthreads();
    if (t < HID) {
        float acc = bb1[t];
#pragma unroll 8
        for (int k = 0; k < HC; k++) acc += sg[k] * w1[(size_t)k * HID + t];
        st[t] = acc;
    }
    __syncthreads();
    if (t < OUT_CH) {
        float acc = bb2[t];
#pragma unroll
        for (int k = 0; k < HID; k++) acc += st[k] * w2[(size_t)k * OUT_CH + t];
        out[(size_t)b * OUT_CH + t] = acc;
    }
}

extern "C" void kernel_launch(void* const* d_in, const int* in_sizes, int n_in,
                              void* d_out, int out_size, void* d_ws, size_t ws_size,
                              hipStream_t stream) {
    const float* x       = (const float*)d_in[0];
    const int*   ei      = (const int*)d_in[1];
    const int*   batch   = (const int*)d_in[2];
    const float* W1      = (const float*)d_in[3];
    const float* att_src = (const float*)d_in[4];
    const float* att_dst = (const float*)d_in[5];
    const float* b1      = (const float*)d_in[6];
    const float* lin1_w  = (const float*)d_in[7];
    const float* lin1_b  = (const float*)d_in[8];
    const float* lin2_w  = (const float*)d_in[9];
    const float* lin2_b  = (const float*)d_in[10];
    float* out = (float*)d_out;

    float* ws = (float*)d_ws;
    // layout (float-offsets into ws):
    unsigned short* hb   = (unsigned short*)ws;    // N*128 bf16 -> 3,200,000 floats
    float*  a_s      = ws + 3200000;               //   200,000
    float*  a_d      = ws + 3400000;               //   200,000
    unsigned int* ebuf = (unsigned int*)(ws + 3600000);     // NB*PCAP = 512*3552 = 1,818,624
    unsigned short* whiF = (unsigned short*)(ws + 5418624); // 16384 us = 8192 floats
    unsigned short* wloF = (unsigned short*)(ws + 5426816); // 16384 us = 8192 floats
    int*    gcur     = (int*)(ws + 5435008);       //       512
    float*  g        = ws + 5436000;               //    65,536
    // total ~5.5M floats = 22 MB (same footprint as R15-27)

    k_prep<<<64, 256, 0, stream>>>(W1, whiF, wloF, gcur);
    k_fused<<<TOT_BLOCKS, 256, 0, stream>>>(
        x, whiF, wloF, att_src, att_dst, ei, hb, a_s, a_d, gcur, ebuf, g);
    k_aggB<<<NB, 1024, 0, stream>>>(ebuf, gcur, a_s, a_d, hb, b1, batch, g);
    k_mlp<<<B_GRAPHS, 64, 0, stream>>>(g, lin1_w, lin1_b, lin2_w, lin2_b, out);
}